// Round 1
// baseline (798.094 us; speedup 1.0000x reference)
//
#include <hip/hip_runtime.h>
#include <hip/hip_bf16.h>

#define N_TOK 4096
#define H_DIM 1024
#define V_DIM 50257
#define IGNORE_IDX (-100)
#define BM 128
#define BN 128
#define BK 64
#define NCHUNK ((V_DIM + BN - 1) / BN)   /* 393 */
#define LDT 72                           /* padded LDS row stride (elems): 144 B -> 2-way bank alias only */

typedef __attribute__((ext_vector_type(8))) short bf16x8;
typedef __attribute__((ext_vector_type(4))) float f32x4;

union Pack8 { __hip_bfloat162 h2[4]; int4 v; };

// ---------------- Kernel 1: x fp32 -> bf16 ----------------
__global__ __launch_bounds__(256) void cvt_x_kernel(const float* __restrict__ x,
                                                    __hip_bfloat16* __restrict__ xb) {
    size_t e = (size_t)blockIdx.x * 256 + threadIdx.x;   // 8 floats per thread
    const float4* s = reinterpret_cast<const float4*>(x) + e * 2;
    float4 a = s[0], b = s[1];
    Pack8 p;
    p.h2[0] = __float22bfloat162_rn(make_float2(a.x, a.y));
    p.h2[1] = __float22bfloat162_rn(make_float2(a.z, a.w));
    p.h2[2] = __float22bfloat162_rn(make_float2(b.x, b.y));
    p.h2[3] = __float22bfloat162_rn(make_float2(b.z, b.w));
    reinterpret_cast<int4*>(xb)[e] = p.v;
}

// ---------------- Kernel 2: fused GEMM + per-chunk online softmax stats ----------------
// grid = (N/BM, NCHUNK), block = 256 (4 waves, 2x2 of 64x64)
__global__ __launch_bounds__(256) void ce_gemm_kernel(
        const __hip_bfloat16* __restrict__ xb,   // [N][H] bf16
        const float* __restrict__ W,             // [V][H] fp32
        const int* __restrict__ tgt,             // [N]
        float2* __restrict__ partials,           // [N][NCHUNK]  (max, sumexp)
        float* __restrict__ picked) {            // [N]
    __shared__ __hip_bfloat16 lA[BM * LDT];
    __shared__ __hip_bfloat16 lB[BN * LDT];
    __shared__ float2 mergebuf[BM][2];
    __shared__ int ltgt[BM];

    const int tid  = threadIdx.x;
    const int mb   = blockIdx.x;         // row tile (fast dim -> 32 consecutive blocks share one W chunk)
    const int vb   = blockIdx.y;         // vocab chunk
    const int rbase = mb * BM;
    const int cbase = vb * BN;
    const int lane = tid & 63;
    const int wid  = tid >> 6;
    const int wr   = wid >> 1;           // wave row (0..1)
    const int wc   = wid & 1;            // wave col (0..1)
    const int l15  = lane & 15;
    const int lg   = lane >> 4;          // 0..3

    if (tid < BM) ltgt[tid] = tgt[rbase + tid];

    f32x4 acc[4][4] = {};

    for (int s = 0; s < H_DIM / BK; ++s) {
        const int k0 = s * BK;
        __syncthreads();
        // ---- stage A (bf16 source): 128x64 elems, 8 bf16 (16B) per ld/st ----
        #pragma unroll
        for (int it = 0; it < 4; ++it) {
            int e = it * 256 + tid;          // 0..1023
            int r = e >> 3, c8 = e & 7;
            int4 v = *reinterpret_cast<const int4*>(xb + (size_t)(rbase + r) * H_DIM + k0 + c8 * 8);
            *reinterpret_cast<int4*>(&lA[r * LDT + c8 * 8]) = v;
        }
        // ---- stage B (fp32 source, convert in-register): 128x64 elems ----
        #pragma unroll
        for (int it = 0; it < 4; ++it) {
            int e = it * 256 + tid;
            int r = e >> 3, c8 = e & 7;
            int v = cbase + r; if (v >= V_DIM) v = V_DIM - 1;   // clamp; masked in epilogue
            const float4* src = reinterpret_cast<const float4*>(W + (size_t)v * H_DIM + k0 + c8 * 8);
            float4 f0 = src[0], f1 = src[1];
            Pack8 p;
            p.h2[0] = __float22bfloat162_rn(make_float2(f0.x, f0.y));
            p.h2[1] = __float22bfloat162_rn(make_float2(f0.z, f0.w));
            p.h2[2] = __float22bfloat162_rn(make_float2(f1.x, f1.y));
            p.h2[3] = __float22bfloat162_rn(make_float2(f1.z, f1.w));
            *reinterpret_cast<int4*>(&lB[r * LDT + c8 * 8]) = p.v;
        }
        __syncthreads();
        // ---- MFMA: two K=32 steps per stage ----
        #pragma unroll
        for (int kk = 0; kk < 2; ++kk) {
            bf16x8 af[4], bfr[4];
            #pragma unroll
            for (int m = 0; m < 4; ++m)
                af[m] = *reinterpret_cast<const bf16x8*>(
                    &lA[(wr * 64 + m * 16 + l15) * LDT + kk * 32 + lg * 8]);
            #pragma unroll
            for (int n = 0; n < 4; ++n)
                bfr[n] = *reinterpret_cast<const bf16x8*>(
                    &lB[(wc * 64 + n * 16 + l15) * LDT + kk * 32 + lg * 8]);
            #pragma unroll
            for (int m = 0; m < 4; ++m)
                #pragma unroll
                for (int n = 0; n < 4; ++n)
                    acc[m][n] = __builtin_amdgcn_mfma_f32_16x16x32_bf16(af[m], bfr[n], acc[m][n], 0, 0, 0);
        }
    }

    // ---- fused epilogue: per-row (max, sumexp) over this 128-col chunk + target pick ----
    // C layout: col = lane&15, row = (lane>>4)*4 + reg
    #pragma unroll
    for (int m = 0; m < 4; ++m) {
        #pragma unroll
        for (int j = 0; j < 4; ++j) {
            int rl = wr * 64 + m * 16 + lg * 4 + j;     // local row
            int tg = ltgt[rl];
            float v4[4];
            float vmax = -INFINITY;
            #pragma unroll
            for (int n = 0; n < 4; ++n) {
                int cg = cbase + wc * 64 + n * 16 + l15;
                float val = acc[m][n][j];
                bool ok = cg < V_DIM;
                v4[n] = ok ? val : -INFINITY;
                if (ok && tg == cg) picked[rbase + rl] = val;
                vmax = fmaxf(vmax, v4[n]);
            }
            #pragma unroll
            for (int msk = 1; msk <= 8; msk <<= 1)
                vmax = fmaxf(vmax, __shfl_xor(vmax, msk));
            float ssum = 0.f;
            #pragma unroll
            for (int n = 0; n < 4; ++n)
                ssum += (v4[n] == -INFINITY) ? 0.f : __expf(v4[n] - vmax);
            #pragma unroll
            for (int msk = 1; msk <= 8; msk <<= 1)
                ssum += __shfl_xor(ssum, msk);
            if (l15 == 0) mergebuf[rl][wc] = make_float2(vmax, ssum);
        }
    }
    __syncthreads();
    if (tid < BM) {
        float2 p0 = mergebuf[tid][0], p1 = mergebuf[tid][1];
        float M = fmaxf(p0.x, p1.x);
        float sm = 0.f;
        if (p0.x > -INFINITY) sm += p0.y * __expf(p0.x - M);
        if (p1.x > -INFINITY) sm += p1.y * __expf(p1.x - M);
        partials[(size_t)(rbase + tid) * NCHUNK + vb] = make_float2(M, sm);
    }
}

// ---------------- Kernel 3: per-row logsumexp merge + loss partial sums ----------------
// grid = 64 blocks x 256 threads (4 waves); wave w handles rows w, w+256, ...
__global__ __launch_bounds__(256) void ce_combine_kernel(
        const float2* __restrict__ partials, const float* __restrict__ picked,
        const int* __restrict__ tgt, float2* __restrict__ blockSums) {
    __shared__ float2 wsum[4];
    int tid = threadIdx.x, lane = tid & 63, wave = tid >> 6;
    int w = blockIdx.x * 4 + wave;       // 0..255
    float sum = 0.f, cnt = 0.f;
    for (int row = w; row < N_TOK; row += 256) {
        float m = -INFINITY, sacc = 0.f;
        for (int c = lane; c < NCHUNK; c += 64) {
            float2 p = partials[(size_t)row * NCHUNK + c];
            float M = fmaxf(m, p.x);
            sacc = sacc * __expf(m - M) + p.y * __expf(p.x - M);
            m = M;
        }
        #pragma unroll
        for (int msk = 1; msk < 64; msk <<= 1) {
            float om = __shfl_xor(m, msk), os = __shfl_xor(sacc, msk);
            float M = fmaxf(m, om);
            sacc = sacc * __expf(m - M) + os * __expf(om - M);
            m = M;
        }
        if (lane == 0) {
            int t = tgt[row];
            if (t != IGNORE_IDX) {
                sum += (m + __logf(sacc)) - picked[row];
                cnt += 1.f;
            }
        }
    }
    if (lane == 0) wsum[wave] = make_float2(sum, cnt);
    __syncthreads();
    if (tid == 0) {
        float S = 0.f, C = 0.f;
        #pragma unroll
        for (int i = 0; i < 4; ++i) { S += wsum[i].x; C += wsum[i].y; }
        blockSums[blockIdx.x] = make_float2(S, C);
    }
}

// ---------------- Kernel 4: final scalar ----------------
__global__ void ce_final_kernel(const float2* __restrict__ blockSums, float* __restrict__ out) {
    int lane = threadIdx.x;              // 64 threads
    float2 p = blockSums[lane];
    float S = p.x, C = p.y;
    #pragma unroll
    for (int msk = 1; msk < 64; msk <<= 1) {
        S += __shfl_xor(S, msk);
        C += __shfl_xor(C, msk);
    }
    if (lane == 0) out[0] = S / fmaxf(C, 1.f);
}

extern "C" void kernel_launch(void* const* d_in, const int* in_sizes, int n_in,
                              void* d_out, int out_size, void* d_ws, size_t ws_size,
                              hipStream_t stream) {
    const float* x   = (const float*)d_in[0];
    const int*   tgt = (const int*)d_in[1];
    const float* W   = (const float*)d_in[2];
    float* out = (float*)d_out;

    // ws layout (needs ~21.2 MiB):
    //   [0, 8M)        x as bf16
    //   [8M, 21M)      partials float2 [N][NCHUNK]  (12.3 MiB)
    //   [21M, +16K)    picked float [N]
    //   [+64K, +512)   blockSums float2 [64]
    char* ws = (char*)d_ws;
    __hip_bfloat16* xb = (__hip_bfloat16*)ws;
    float2* partials   = (float2*)(ws + (8u << 20));
    float*  picked     = (float*)(ws + (21u << 20));
    float2* blockSums  = (float2*)(ws + (21u << 20) + (64u << 10));

    cvt_x_kernel<<<(N_TOK * H_DIM) / (256 * 8), 256, 0, stream>>>(x, xb);

    dim3 grid(N_TOK / BM, NCHUNK);   // x = row-tile (fast): consecutive blocks share W chunk
    ce_gemm_kernel<<<grid, 256, 0, stream>>>(xb, W, tgt, partials, picked);

    ce_combine_kernel<<<64, 256, 0, stream>>>(partials, picked, tgt, blockSums);
    ce_final_kernel<<<1, 64, 0, stream>>>(blockSums, out);
}

// Round 2
// 571.698 us; speedup vs baseline: 1.3960x; 1.3960x over previous
//
#include <hip/hip_runtime.h>
#include <hip/hip_bf16.h>

#define N_TOK 4096
#define H_DIM 1024
#define V_DIM 50257
#define IGNORE_IDX (-100)
#define BM 128
#define BN 128
#define BK 64
#define NCHUNK ((V_DIM + BN - 1) / BN)   /* 393 */
#define LDT 72                           /* fallback-path padded LDS stride */

typedef __attribute__((ext_vector_type(8))) short bf16x8;
typedef __attribute__((ext_vector_type(4))) float f32x4;

union Pack8 { __hip_bfloat162 h2[4]; int4 v; };

// ---- global_load_lds: 16B per lane, LDS dest = wave-uniform base + lane*16 ----
__device__ __forceinline__ void gload16(const void* g, void* l) {
    __builtin_amdgcn_global_load_lds(
        (const __attribute__((address_space(1))) unsigned int*)g,
        (__attribute__((address_space(3))) unsigned int*)l,
        16, 0, 0);
}

// ---------------- cvt kernels ----------------
__global__ __launch_bounds__(256) void cvt_x_kernel(const float* __restrict__ x,
                                                    __hip_bfloat16* __restrict__ xb) {
    size_t e = (size_t)blockIdx.x * 256 + threadIdx.x;   // 8 floats per thread
    const float4* s = reinterpret_cast<const float4*>(x) + e * 2;
    float4 a = s[0], b = s[1];
    Pack8 p;
    p.h2[0] = __float22bfloat162_rn(make_float2(a.x, a.y));
    p.h2[1] = __float22bfloat162_rn(make_float2(a.z, a.w));
    p.h2[2] = __float22bfloat162_rn(make_float2(b.x, b.y));
    p.h2[3] = __float22bfloat162_rn(make_float2(b.z, b.w));
    reinterpret_cast<int4*>(xb)[e] = p.v;
}

__global__ __launch_bounds__(256) void cvt_w_kernel(const float* __restrict__ W,
                                                    __hip_bfloat16* __restrict__ Wb) {
    const size_t total = (size_t)V_DIM * H_DIM / 8;   // granules of 8 floats
    size_t stride = (size_t)gridDim.x * 256;
    for (size_t e = (size_t)blockIdx.x * 256 + threadIdx.x; e < total; e += stride) {
        const float4* s = reinterpret_cast<const float4*>(W) + e * 2;
        float4 a = s[0], b = s[1];
        Pack8 p;
        p.h2[0] = __float22bfloat162_rn(make_float2(a.x, a.y));
        p.h2[1] = __float22bfloat162_rn(make_float2(a.z, a.w));
        p.h2[2] = __float22bfloat162_rn(make_float2(b.x, b.y));
        p.h2[3] = __float22bfloat162_rn(make_float2(b.z, b.w));
        reinterpret_cast<int4*>(Wb)[e] = p.v;
    }
}

// ---------------- FAST GEMM: global_load_lds + pre-swizzled source (m97 structure) ----------------
// grid = (N/BM, NCHUNK), block = 256 (4 waves, 2x2 of 64x64)
__global__ __launch_bounds__(256, 4) void ce_gemm_fast(
        const __hip_bfloat16* __restrict__ xb,   // [N][H] bf16
        const __hip_bfloat16* __restrict__ Wb,   // [V][H] bf16
        const int* __restrict__ tgt,
        float2* __restrict__ partials,           // [N][NCHUNK]
        float* __restrict__ picked) {            // [N]
    __shared__ __hip_bfloat16 lA[BM * BK];       // 16 KB, linear, source-swizzled
    __shared__ __hip_bfloat16 lB[BN * BK];       // 16 KB
    __shared__ float2 mergebuf[BM][2];
    __shared__ int ltgt[BM];

    const int tid  = threadIdx.x;
    const int mb   = blockIdx.x;     // row tile fast -> 32 consecutive blocks share one W chunk
    const int vb   = blockIdx.y;
    const int rbase = mb * BM;
    const int cbase = vb * BN;
    const int lane = tid & 63;
    const int wid  = tid >> 6;
    const int wr   = wid >> 1;
    const int wc   = wid & 1;
    const int l15  = lane & 15;
    const int lg   = lane >> 4;

    if (tid < BM) ltgt[tid] = tgt[rbase + tid];

    // Staging plan: granule G = wid*256 + i*64 + lane (16B each), LDS byte = G*16 (linear).
    // Source pre-swizzle (m173): LDS slot (r=G>>3, j=G&7) holds global granule (r, j^(r&7)).
    int rowS[4], colS[4];
    #pragma unroll
    for (int i = 0; i < 4; ++i) {
        int G = wid * 256 + i * 64 + lane;
        int r = G >> 3;
        rowS[i] = r;
        colS[i] = ((G & 7) ^ (r & 7)) * 8;       // bf16-elem offset within K-slab
    }

    f32x4 acc[4][4] = {};

    for (int s = 0; s < H_DIM / BK; ++s) {
        const int k0 = s * BK;
        __syncthreads();                          // prior MFMA reads done before overwrite
        #pragma unroll
        for (int i = 0; i < 4; ++i) {
            const __hip_bfloat16* gA = xb + (size_t)(rbase + rowS[i]) * H_DIM + k0 + colS[i];
            gload16(gA, (char*)lA + (wid * 256 + i * 64) * 16);
            int vr = cbase + rowS[i]; if (vr >= V_DIM) vr = V_DIM - 1;   // clamp; masked in epilogue
            const __hip_bfloat16* gB = Wb + (size_t)vr * H_DIM + k0 + colS[i];
            gload16(gB, (char*)lB + (wid * 256 + i * 64) * 16);
        }
        __syncthreads();                          // compiler drains vmcnt before barrier
        #pragma unroll
        for (int kk = 0; kk < 2; ++kk) {
            bf16x8 af[4], bfr[4];
            const int g = kk * 4 + lg;            // 16B-granule index within row
            #pragma unroll
            for (int m = 0; m < 4; ++m) {
                int r = wr * 64 + m * 16 + l15;
                af[m] = *reinterpret_cast<const bf16x8*>(
                    (char*)lA + r * 128 + ((g ^ (r & 7)) * 16));
            }
            #pragma unroll
            for (int n = 0; n < 4; ++n) {
                int r = wc * 64 + n * 16 + l15;
                bfr[n] = *reinterpret_cast<const bf16x8*>(
                    (char*)lB + r * 128 + ((g ^ (r & 7)) * 16));
            }
            #pragma unroll
            for (int m = 0; m < 4; ++m)
                #pragma unroll
                for (int n = 0; n < 4; ++n)
                    acc[m][n] = __builtin_amdgcn_mfma_f32_16x16x32_bf16(af[m], bfr[n], acc[m][n], 0, 0, 0);
        }
    }

    // ---- fused epilogue: per-row (max, sumexp) over this 128-col chunk + target pick ----
    #pragma unroll
    for (int m = 0; m < 4; ++m) {
        #pragma unroll
        for (int j = 0; j < 4; ++j) {
            int rl = wr * 64 + m * 16 + lg * 4 + j;
            int tg = ltgt[rl];
            float v4[4];
            float vmax = -INFINITY;
            #pragma unroll
            for (int n = 0; n < 4; ++n) {
                int cg = cbase + wc * 64 + n * 16 + l15;
                float val = acc[m][n][j];
                bool ok = cg < V_DIM;
                v4[n] = ok ? val : -INFINITY;
                if (ok && tg == cg) picked[rbase + rl] = val;
                vmax = fmaxf(vmax, v4[n]);
            }
            #pragma unroll
            for (int msk = 1; msk <= 8; msk <<= 1)
                vmax = fmaxf(vmax, __shfl_xor(vmax, msk));
            float ssum = 0.f;
            #pragma unroll
            for (int n = 0; n < 4; ++n)
                ssum += (v4[n] == -INFINITY) ? 0.f : __expf(v4[n] - vmax);
            #pragma unroll
            for (int msk = 1; msk <= 8; msk <<= 1)
                ssum += __shfl_xor(ssum, msk);
            if (l15 == 0) mergebuf[rl][wc] = make_float2(vmax, ssum);
        }
    }
    __syncthreads();
    if (tid < BM) {
        float2 p0 = mergebuf[tid][0], p1 = mergebuf[tid][1];
        float M = fmaxf(p0.x, p1.x);
        float sm = 0.f;
        if (p0.x > -INFINITY) sm += p0.y * __expf(p0.x - M);
        if (p1.x > -INFINITY) sm += p1.y * __expf(p1.x - M);
        partials[(size_t)(rbase + tid) * NCHUNK + vb] = make_float2(M, sm);
    }
}

// ---------------- FALLBACK GEMM (round-1 path, fp32 W, in-register cvt) ----------------
__global__ __launch_bounds__(256) void ce_gemm_kernel(
        const __hip_bfloat16* __restrict__ xb, const float* __restrict__ W,
        const int* __restrict__ tgt, float2* __restrict__ partials, float* __restrict__ picked) {
    __shared__ __hip_bfloat16 lA[BM * LDT];
    __shared__ __hip_bfloat16 lB[BN * LDT];
    __shared__ float2 mergebuf[BM][2];
    __shared__ int ltgt[BM];
    const int tid = threadIdx.x, mb = blockIdx.x, vb = blockIdx.y;
    const int rbase = mb * BM, cbase = vb * BN;
    const int lane = tid & 63, wid = tid >> 6;
    const int wr = wid >> 1, wc = wid & 1, l15 = lane & 15, lg = lane >> 4;
    if (tid < BM) ltgt[tid] = tgt[rbase + tid];
    f32x4 acc[4][4] = {};
    for (int s = 0; s < H_DIM / BK; ++s) {
        const int k0 = s * BK;
        __syncthreads();
        #pragma unroll
        for (int it = 0; it < 4; ++it) {
            int e = it * 256 + tid, r = e >> 3, c8 = e & 7;
            int4 v = *reinterpret_cast<const int4*>(xb + (size_t)(rbase + r) * H_DIM + k0 + c8 * 8);
            *reinterpret_cast<int4*>(&lA[r * LDT + c8 * 8]) = v;
        }
        #pragma unroll
        for (int it = 0; it < 4; ++it) {
            int e = it * 256 + tid, r = e >> 3, c8 = e & 7;
            int v = cbase + r; if (v >= V_DIM) v = V_DIM - 1;
            const float4* src = reinterpret_cast<const float4*>(W + (size_t)v * H_DIM + k0 + c8 * 8);
            float4 f0 = src[0], f1 = src[1];
            Pack8 p;
            p.h2[0] = __float22bfloat162_rn(make_float2(f0.x, f0.y));
            p.h2[1] = __float22bfloat162_rn(make_float2(f0.z, f0.w));
            p.h2[2] = __float22bfloat162_rn(make_float2(f1.x, f1.y));
            p.h2[3] = __float22bfloat162_rn(make_float2(f1.z, f1.w));
            *reinterpret_cast<int4*>(&lB[r * LDT + c8 * 8]) = p.v;
        }
        __syncthreads();
        #pragma unroll
        for (int kk = 0; kk < 2; ++kk) {
            bf16x8 af[4], bfr[4];
            #pragma unroll
            for (int m = 0; m < 4; ++m)
                af[m] = *reinterpret_cast<const bf16x8*>(&lA[(wr * 64 + m * 16 + l15) * LDT + kk * 32 + lg * 8]);
            #pragma unroll
            for (int n = 0; n < 4; ++n)
                bfr[n] = *reinterpret_cast<const bf16x8*>(&lB[(wc * 64 + n * 16 + l15) * LDT + kk * 32 + lg * 8]);
            #pragma unroll
            for (int m = 0; m < 4; ++m)
                #pragma unroll
                for (int n = 0; n < 4; ++n)
                    acc[m][n] = __builtin_amdgcn_mfma_f32_16x16x32_bf16(af[m], bfr[n], acc[m][n], 0, 0, 0);
        }
    }
    #pragma unroll
    for (int m = 0; m < 4; ++m) {
        #pragma unroll
        for (int j = 0; j < 4; ++j) {
            int rl = wr * 64 + m * 16 + lg * 4 + j;
            int tg = ltgt[rl];
            float v4[4]; float vmax = -INFINITY;
            #pragma unroll
            for (int n = 0; n < 4; ++n) {
                int cg = cbase + wc * 64 + n * 16 + l15;
                float val = acc[m][n][j];
                bool ok = cg < V_DIM;
                v4[n] = ok ? val : -INFINITY;
                if (ok && tg == cg) picked[rbase + rl] = val;
                vmax = fmaxf(vmax, v4[n]);
            }
            #pragma unroll
            for (int msk = 1; msk <= 8; msk <<= 1) vmax = fmaxf(vmax, __shfl_xor(vmax, msk));
            float ssum = 0.f;
            #pragma unroll
            for (int n = 0; n < 4; ++n) ssum += (v4[n] == -INFINITY) ? 0.f : __expf(v4[n] - vmax);
            #pragma unroll
            for (int msk = 1; msk <= 8; msk <<= 1) ssum += __shfl_xor(ssum, msk);
            if (l15 == 0) mergebuf[rl][wc] = make_float2(vmax, ssum);
        }
    }
    __syncthreads();
    if (tid < BM) {
        float2 p0 = mergebuf[tid][0], p1 = mergebuf[tid][1];
        float M = fmaxf(p0.x, p1.x);
        float sm = 0.f;
        if (p0.x > -INFINITY) sm += p0.y * __expf(p0.x - M);
        if (p1.x > -INFINITY) sm += p1.y * __expf(p1.x - M);
        partials[(size_t)(rbase + tid) * NCHUNK + vb] = make_float2(M, sm);
    }
}

// ---------------- combine + final ----------------
__global__ __launch_bounds__(256) void ce_combine_kernel(
        const float2* __restrict__ partials, const float* __restrict__ picked,
        const int* __restrict__ tgt, float2* __restrict__ blockSums) {
    __shared__ float2 wsum[4];
    int tid = threadIdx.x, lane = tid & 63, wave = tid >> 6;
    int w = blockIdx.x * 4 + wave;
    float sum = 0.f, cnt = 0.f;
    for (int row = w; row < N_TOK; row += 256) {
        float m = -INFINITY, sacc = 0.f;
        for (int c = lane; c < NCHUNK; c += 64) {
            float2 p = partials[(size_t)row * NCHUNK + c];
            float M = fmaxf(m, p.x);
            sacc = sacc * __expf(m - M) + p.y * __expf(p.x - M);
            m = M;
        }
        #pragma unroll
        for (int msk = 1; msk < 64; msk <<= 1) {
            float om = __shfl_xor(m, msk), os = __shfl_xor(sacc, msk);
            float M = fmaxf(m, om);
            sacc = sacc * __expf(m - M) + os * __expf(om - M);
            m = M;
        }
        if (lane == 0) {
            int t = tgt[row];
            if (t != IGNORE_IDX) { sum += (m + __logf(sacc)) - picked[row]; cnt += 1.f; }
        }
    }
    if (lane == 0) wsum[wave] = make_float2(sum, cnt);
    __syncthreads();
    if (tid == 0) {
        float S = 0.f, C = 0.f;
        #pragma unroll
        for (int i = 0; i < 4; ++i) { S += wsum[i].x; C += wsum[i].y; }
        blockSums[blockIdx.x] = make_float2(S, C);
    }
}

__global__ void ce_final_kernel(const float2* __restrict__ blockSums, float* __restrict__ out) {
    int lane = threadIdx.x;
    float2 p = blockSums[lane];
    float S = p.x, C = p.y;
    #pragma unroll
    for (int msk = 1; msk < 64; msk <<= 1) { S += __shfl_xor(S, msk); C += __shfl_xor(C, msk); }
    if (lane == 0) out[0] = S / fmaxf(C, 1.f);
}

extern "C" void kernel_launch(void* const* d_in, const int* in_sizes, int n_in,
                              void* d_out, int out_size, void* d_ws, size_t ws_size,
                              hipStream_t stream) {
    const float* x   = (const float*)d_in[0];
    const int*   tgt = (const int*)d_in[1];
    const float* W   = (const float*)d_in[2];
    float* out = (float*)d_out;
    char* ws = (char*)d_ws;

    if (ws_size >= ((size_t)142 << 20)) {
        // fast path: xb@0 (8.4MB), Wb@16MB (103MB), partials@120MB (12.9MB),
        // picked@140MB (16KB), blockSums@141MB
        __hip_bfloat16* xb = (__hip_bfloat16*)ws;
        __hip_bfloat16* Wb = (__hip_bfloat16*)(ws + ((size_t)16 << 20));
        float2* partials   = (float2*)(ws + ((size_t)120 << 20));
        float*  picked     = (float*)(ws + ((size_t)140 << 20));
        float2* blockSums  = (float2*)(ws + ((size_t)141 << 20));

        cvt_x_kernel<<<(N_TOK * H_DIM) / (256 * 8), 256, 0, stream>>>(x, xb);
        cvt_w_kernel<<<2048, 256, 0, stream>>>(W, Wb);
        dim3 grid(N_TOK / BM, NCHUNK);
        ce_gemm_fast<<<grid, 256, 0, stream>>>(xb, Wb, tgt, partials, picked);
        ce_combine_kernel<<<64, 256, 0, stream>>>(partials, picked, tgt, blockSums);
        ce_final_kernel<<<1, 64, 0, stream>>>(blockSums, out);
    } else {
        // fallback (round-1 layout)
        __hip_bfloat16* xb = (__hip_bfloat16*)ws;
        float2* partials   = (float2*)(ws + (8u << 20));
        float*  picked     = (float*)(ws + (21u << 20));
        float2* blockSums  = (float2*)(ws + (21u << 20) + (64u << 10));

        cvt_x_kernel<<<(N_TOK * H_DIM) / (256 * 8), 256, 0, stream>>>(x, xb);
        dim3 grid(N_TOK / BM, NCHUNK);
        ce_gemm_kernel<<<grid, 256, 0, stream>>>(xb, W, tgt, partials, picked);
        ce_combine_kernel<<<64, 256, 0, stream>>>(partials, picked, tgt, blockSums);
        ce_final_kernel<<<1, 64, 0, stream>>>(blockSums, out);
    }
}